// Round 8
// baseline (135.339 us; speedup 1.0000x reference)
//
#include <hip/hip_runtime.h>

// Problem constants: B=2, N=2048, C=1024, H=16, hd=64
// x:(2,2048,1024) f32; Wqkv:(1024,3072); Wproj:(1024,1024); bproj:(1024); q_scale,k_scale:(64)
// out:(2,2048,1024) f32

typedef _Float16 half_t;
typedef __attribute__((ext_vector_type(2))) __fp16 fp16x2;
typedef __attribute__((ext_vector_type(4))) _Float16 half4v;
typedef __attribute__((ext_vector_type(8))) _Float16 half8;
typedef __attribute__((ext_vector_type(4))) float f32x4;

#define DI __device__ __forceinline__

DI void gl_lds16(const void* g, void* l) {
    __builtin_amdgcn_global_load_lds((const __attribute__((address_space(1))) void*)g,
                                     (__attribute__((address_space(3))) void*)l, 16, 0, 0);
}

DI float exp2_fast(float x) {
    float r;
    asm("v_exp_f32 %0, %1" : "=v"(r) : "v"(x));
    return r;
}

// ---------------- merged prep kernel ----------------
// blocks [0,4096): x f32->fp16 ; [4096,7168): Wqkv transpose->fp16 ; [7168,8192): Wproj
__global__ void prep_all(const float* __restrict__ x, const float* __restrict__ Wqkv,
                         const float* __restrict__ Wproj, half_t* __restrict__ xh,
                         half_t* __restrict__ wqt, half_t* __restrict__ wpt) {
    __shared__ float t[32][33];
    int bid = blockIdx.x;
    if (bid < 4096) {
        int i = (bid * 256 + threadIdx.x) * 4;
        float4 v = *(const float4*)(x + i);
        half4v o;
        o[0] = (half_t)v.x; o[1] = (half_t)v.y; o[2] = (half_t)v.z; o[3] = (half_t)v.w;
        *(half4v*)(xh + i) = o;
    } else if (bid < 4096 + 3072) {
        int i = bid - 4096;
        int c0 = (i % 96) * 32, r0 = (i / 96) * 32;
        int tx = threadIdx.x & 31, ty = threadIdx.x >> 5;
#pragma unroll
        for (int k = 0; k < 4; k++)
            t[ty + 8 * k][tx] = Wqkv[(size_t)(r0 + ty + 8 * k) * 3072 + c0 + tx];
        __syncthreads();
#pragma unroll
        for (int k = 0; k < 4; k++)
            wqt[(size_t)(c0 + ty + 8 * k) * 1024 + r0 + tx] = (half_t)t[tx][ty + 8 * k];
    } else {
        int i = bid - 4096 - 3072;
        int c0 = (i % 32) * 32, r0 = (i / 32) * 32;
        int tx = threadIdx.x & 31, ty = threadIdx.x >> 5;
#pragma unroll
        for (int k = 0; k < 4; k++)
            t[ty + 8 * k][tx] = Wproj[(size_t)(r0 + ty + 8 * k) * 1024 + c0 + tx];
        __syncthreads();
#pragma unroll
        for (int k = 0; k < 4; k++)
            wpt[(size_t)(c0 + ty + 8 * k) * 1024 + r0 + tx] = (half_t)t[tx][ty + 8 * k];
    }
}

// ---------------- QKV GEMM: fp16, BK=64, dbuf LDS, fused RMSNorm epilogue ----------------
__global__ __launch_bounds__(256) void gemm_qkv(
    const half_t* __restrict__ A, const half_t* __restrict__ Bt,
    const float* __restrict__ qs, const float* __restrict__ ks,
    half_t* __restrict__ qh, half_t* __restrict__ kh, half_t* __restrict__ vth) {
    const int K = 1024;
    __shared__ __align__(16) half_t Al[2][128 * 64];
    __shared__ __align__(16) half_t Bl[2][128 * 64];
    int tid = threadIdx.x;
    int w = tid >> 6, l = tid & 63;
    int wr = w >> 1, wc = w & 1;
    int g = l >> 4, r = l & 15;
    int m0 = blockIdx.x * 128, n0 = blockIdx.y * 128;
    f32x4 acc[4][4] = {};

#define STAGE_QKV(kt, buf)                                                        \
    {                                                                             \
        _Pragma("unroll")                                                         \
        for (int p = 0; p < 4; p++) {                                             \
            int ci = p * 256 + tid;                                               \
            int row = ci >> 3, c = ci & 7, lc = c ^ (row & 7);                    \
            gl_lds16(A + (size_t)(m0 + row) * K + (kt) * 64 + lc * 8,             \
                     &Al[buf][0] + ci * 8);                                       \
            gl_lds16(Bt + (size_t)(n0 + row) * K + (kt) * 64 + lc * 8,            \
                     &Bl[buf][0] + ci * 8);                                       \
        }                                                                         \
    }

    STAGE_QKV(0, 0);
    __syncthreads();
    int cur = 0;
    for (int kt = 0; kt < 16; kt++) {
        if (kt < 15) STAGE_QKV(kt + 1, cur ^ 1);
#pragma unroll
        for (int ks2 = 0; ks2 < 2; ks2++) {
            half8 af[4], bf[4];
#pragma unroll
            for (int i = 0; i < 4; i++) {
                int row = wr * 64 + i * 16 + r;
                af[i] = *(const half8*)(&Al[cur][0] + row * 64 + (((4 * ks2 + g) ^ (row & 7)) << 3));
                int rowb = wc * 64 + i * 16 + r;
                bf[i] = *(const half8*)(&Bl[cur][0] + rowb * 64 + (((4 * ks2 + g) ^ (rowb & 7)) << 3));
            }
#pragma unroll
            for (int i = 0; i < 4; i++)
#pragma unroll
                for (int j = 0; j < 4; j++)
                    acc[i][j] = __builtin_amdgcn_mfma_f32_16x16x32_f16(af[i], bf[j], acc[i][j], 0, 0, 0);
        }
        __syncthreads();
        cur ^= 1;
    }

    int tsec = n0 >> 10;  // 0=q, 1=k, 2=v (uniform per block)
    if (tsec == 2) {
#pragma unroll
        for (int i = 0; i < 4; i++)
#pragma unroll
            for (int j = 0; j < 4; j++) {
                int gcol = n0 + wc * 64 + j * 16 + r;
                int h = (gcol >> 6) & 15;
                int f = gcol & 63;
                int growb = m0 + wr * 64 + i * 16 + g * 4;
                int b = growb >> 11;
                int n = growb & 2047;
                half4v pv;
#pragma unroll
                for (int rr = 0; rr < 4; rr++) pv[rr] = (half_t)acc[i][j][rr];
                *(half4v*)(vth + ((size_t)(b * 16 + h) * 64 + f) * 2048 + n) = pv;
            }
    } else {
        const float* sc = (tsec == 0) ? qs : ks;
        half_t* dst = (tsec == 0) ? qh : kh;
        float extra = (tsec == 0) ? (0.125f * 1.44269504f) : 1.0f;  // fold hd^-0.5*log2e into q
        float scv[4];
#pragma unroll
        for (int j = 0; j < 4; j++) scv[j] = sc[j * 16 + r];
#pragma unroll
        for (int i = 0; i < 4; i++)
#pragma unroll
            for (int rr = 0; rr < 4; rr++) {
                float ss = 0.f;
#pragma unroll
                for (int j = 0; j < 4; j++) ss += acc[i][j][rr] * acc[i][j][rr];
#pragma unroll
                for (int d = 1; d < 16; d <<= 1) ss += __shfl_xor(ss, d, 64);
                float inv = extra / (sqrtf(ss) * 0.125f + 1e-8f);  // rms = ||row||/8
                int grow = m0 + wr * 64 + i * 16 + g * 4 + rr;
                int b = grow >> 11;
                int n = grow & 2047;
#pragma unroll
                for (int j = 0; j < 4; j++) {
                    int gcol = n0 + wc * 64 + j * 16 + r;
                    int h = (gcol >> 6) & 15;
                    int f = gcol & 63;
                    dst[((size_t)(b * 16 + h) * 2048 + n) * 64 + f] =
                        (half_t)(acc[i][j][rr] * inv * scv[j]);
                }
            }
    }
}

// ---------------- flash attention, swapped-QK in-register softmax (defer-max) --------
// 4-wave blocks (QBLK=64), grid (32 q-tiles, 32 bh) = 1024 blocks, 40KB LDS -> exactly
// 4 blocks/CU (16 waves/CU). Independent per-block barriers let resident blocks drift
// to different tile phases, so one block's softmax (VALU) overlaps another's MFMA;
// s_setprio(1) around MFMA clusters biases the arbiter (T5, proven-attn regime).
// S^T = mfma(K_frag, Q_frag): lane holds S^T[kv=16tt+4g+reg][q=r], log2 units.
// Defer-max THR=11 (PROVEN R5/R7 numerics; no-max variant failed 4.7e-2 — keep max).
// lsum per-lane partial (fac g-uniform), reduced once in epilogue.
__global__ __launch_bounds__(256, 4) void attn(
    const half_t* __restrict__ qh, const half_t* __restrict__ kh,
    const half_t* __restrict__ vth, half_t* __restrict__ aoh) {
    int bh = blockIdx.y;
    int q0 = blockIdx.x * 64;
    const half_t* Qp = qh + (size_t)bh * 2048 * 64;
    const half_t* Kp = kh + (size_t)bh * 2048 * 64;
    const half_t* Vp = vth + (size_t)bh * 64 * 2048;  // (feat, n)
    __shared__ __align__(16) half_t Kl[2][64 * 64];
    __shared__ __align__(16) half_t Vl[2][64 * 64];   // [feat][kv]
    __shared__ __align__(16) half_t Pl[4][16 * 64];   // per-wave: 16 q x 64 kv (chunk-swizzled)
    int tid = threadIdx.x, w = tid >> 6, l = tid & 63, g = l >> 4, r = l & 15;

    // staging coords: 512 chunks of 16B per 64x64 fp16 buffer, 2 chunks/thread
    const half_t* kstp[2];
    const half_t* vstp[2];
    int ldsoff[2];
#pragma unroll
    for (int p = 0; p < 2; p++) {
        int ci = p * 256 + tid;
        int row = ci >> 3, c = ci & 7, lc = c ^ (row & 7);
        kstp[p] = Kp + (size_t)row * 64 + lc * 8;
        vstp[p] = Vp + (size_t)row * 2048 + lc * 8;
        ldsoff[p] = ci * 8;
    }

    // hoisted LDS element-offsets (loop-invariant)
    int koff[8], voff[8], poffw[4], poffr[2];
#pragma unroll
    for (int ks = 0; ks < 2; ks++)
#pragma unroll
        for (int tt = 0; tt < 4; tt++) {
            int row = tt * 16 + r;
            koff[ks * 4 + tt] = row * 64 + (((4 * ks + g) ^ (row & 7)) << 3);
        }
#pragma unroll
    for (int ks2 = 0; ks2 < 2; ks2++)
#pragma unroll
        for (int cf = 0; cf < 4; cf++) {
            int row = cf * 16 + r;
            voff[ks2 * 4 + cf] = row * 64 + (((4 * ks2 + g) ^ (row & 7)) << 3);
        }
#pragma unroll
    for (int tt = 0; tt < 4; tt++)
        poffw[tt] = r * 64 + (((2 * tt + (g >> 1)) ^ (r & 7)) << 3) + (g & 1) * 4;
#pragma unroll
    for (int ks2 = 0; ks2 < 2; ks2++)
        poffr[ks2] = r * 64 + (((4 * ks2 + g) ^ (r & 7)) << 3);
    half_t* Pw = &Pl[w][0];

    // Q fragment: Q[q=r][hd = 32ks + 8g + e]  (B-operand of swapped QK^T)
    half8 qf[2];
#pragma unroll
    for (int ks = 0; ks < 2; ks++)
        qf[ks] = *(const half8*)(Qp + (size_t)(q0 + w * 16 + r) * 64 + ks * 32 + g * 8);

    f32x4 o[4] = {};          // O^T[d = 16cf + 4g + reg][q = r]
    float m = -1e30f, lsum = 0.f;  // lsum: per-lane partial, reduced in epilogue

    // prologue: stage tile 0
#pragma unroll
    for (int p = 0; p < 2; p++) {
        gl_lds16(kstp[p], &Kl[0][0] + ldsoff[p]);
        gl_lds16(vstp[p], &Vl[0][0] + ldsoff[p]);
    }
    __syncthreads();

#define ATTN_TILE(BUF, T)                                                          \
    {                                                                              \
        if ((T) < 31) {                                                            \
            _Pragma("unroll")                                                      \
            for (int p = 0; p < 2; p++) {                                          \
                gl_lds16(kstp[p] + ((T) + 1) * 4096, &Kl[(BUF) ^ 1][0] + ldsoff[p]); \
                gl_lds16(vstp[p] + ((T) + 1) * 64, &Vl[(BUF) ^ 1][0] + ldsoff[p]); \
            }                                                                      \
        }                                                                          \
        const half_t* Kc = &Kl[BUF][0];                                            \
        const half_t* Vc = &Vl[BUF][0];                                            \
        f32x4 s[4] = {};                                                           \
        __builtin_amdgcn_s_setprio(1);                                             \
        _Pragma("unroll")                                                          \
        for (int ks = 0; ks < 2; ks++)                                             \
            _Pragma("unroll")                                                      \
            for (int tt = 0; tt < 4; tt++) {                                       \
                half8 kf = *(const half8*)(Kc + koff[ks * 4 + tt]);                \
                s[tt] = __builtin_amdgcn_mfma_f32_16x16x32_f16(kf, qf[ks], s[tt], 0, 0, 0); \
            }                                                                      \
        __builtin_amdgcn_s_setprio(0);                                             \
        float mx = -1e30f;                                                         \
        _Pragma("unroll")                                                          \
        for (int tt = 0; tt < 4; tt++)                                             \
            mx = fmaxf(mx, fmaxf(fmaxf(s[tt][0], s[tt][1]), fmaxf(s[tt][2], s[tt][3]))); \
        mx = fmaxf(mx, __shfl_xor(mx, 16, 64));                                    \
        mx = fmaxf(mx, __shfl_xor(mx, 32, 64));                                    \
        if (!__all(mx <= m + 11.0f)) {                                             \
            float mn = fmaxf(m, mx);                                               \
            float fac = exp2_fast(m - mn);                                         \
            lsum *= fac;                                                           \
            _Pragma("unroll")                                                      \
            for (int cf = 0; cf < 4; cf++) {                                       \
                o[cf][0] *= fac; o[cf][1] *= fac; o[cf][2] *= fac; o[cf][3] *= fac; \
            }                                                                      \
            m = mn;                                                                \
        }                                                                          \
        _Pragma("unroll")                                                          \
        for (int tt = 0; tt < 4; tt++)                                             \
            _Pragma("unroll")                                                      \
            for (int e = 0; e < 4; e++) {                                          \
                float p = exp2_fast(s[tt][e] - m);                                 \
                s[tt][e] = p;                                                      \
                lsum += p;                                                         \
            }                                                                      \
        _Pragma("unroll")                                                          \
        for (int tt = 0; tt < 4; tt++) {                                           \
            fp16x2 a = __builtin_amdgcn_cvt_pkrtz(s[tt][0], s[tt][1]);             \
            fp16x2 b = __builtin_amdgcn_cvt_pkrtz(s[tt][2], s[tt][3]);             \
            half4v v4;                                                             \
            v4[0] = (half_t)a[0]; v4[1] = (half_t)a[1];                            \
            v4[2] = (half_t)b[0]; v4[3] = (half_t)b[1];                            \
            *(half4v*)(Pw + poffw[tt]) = v4;                                       \
        }                                                                          \
        _Pragma("unroll")                                                          \
        for (int ks2 = 0; ks2 < 2; ks2++) {                                        \
            half8 pf = *(const half8*)(Pw + poffr[ks2]);                           \
            __builtin_amdgcn_s_setprio(1);                                         \
            _Pragma("unroll")                                                      \
            for (int cf = 0; cf < 4; cf++) {                                       \
                half8 vf = *(const half8*)(Vc + voff[ks2 * 4 + cf]);               \
                o[cf] = __builtin_amdgcn_mfma_f32_16x16x32_f16(vf, pf, o[cf], 0, 0, 0); \
            }                                                                      \
            __builtin_amdgcn_s_setprio(0);                                         \
        }                                                                          \
        __syncthreads();                                                           \
    }

    for (int t = 0; t < 32; t += 2) {
        ATTN_TILE(0, t);
        ATTN_TILE(1, t + 1);
    }

    // cross-lane (g-group) sum: lanes r, r+16, r+32, r+48 hold disjoint kv-slots
    lsum += __shfl_xor(lsum, 16, 64);
    lsum += __shfl_xor(lsum, 32, 64);

    int b = bh >> 4, h = bh & 15;
    int n = q0 + w * 16 + r;
    float inv = 1.0f / lsum;
#pragma unroll
    for (int cf = 0; cf < 4; cf++) {
        half4v ov;
#pragma unroll
        for (int reg = 0; reg < 4; reg++) ov[reg] = (half_t)(o[cf][reg] * inv);
        *(half4v*)(aoh + ((size_t)b * 2048 + n) * 1024 + h * 64 + cf * 16 + g * 4) = ov;
    }
}

// ---------------- proj GEMM: fp16, BK=64, + bias, f32 out ----------------
__global__ __launch_bounds__(256) void gemm_proj(
    const half_t* __restrict__ A, const half_t* __restrict__ Bt,
    const float* __restrict__ bias, float* __restrict__ out) {
    const int K = 1024;
    __shared__ __align__(16) half_t Al[128 * 64];
    __shared__ __align__(16) half_t Bl[128 * 64];
    int tid = threadIdx.x, w = tid >> 6, l = tid & 63;
    int wr = w >> 1, wc = w & 1, g = l >> 4, r = l & 15;
    int m0 = blockIdx.x * 128, n0 = blockIdx.y * 128;
    f32x4 acc[4][4] = {};

    for (int k0 = 0; k0 < K; k0 += 64) {
#pragma unroll
        for (int p = 0; p < 4; p++) {
            int ci = (p * 4 + w) * 64 + l;
            int row = ci >> 3, c = ci & 7;
            int lc = c ^ (row & 7);
            gl_lds16(A + (size_t)(m0 + row) * K + k0 + lc * 8, Al + (p * 4 + w) * 512);
            gl_lds16(Bt + (size_t)(n0 + row) * K + k0 + lc * 8, Bl + (p * 4 + w) * 512);
        }
        __syncthreads();
#pragma unroll
        for (int ks = 0; ks < 2; ks++) {
            half8 af[4], bf[4];
#pragma unroll
            for (int i = 0; i < 4; i++) {
                int row = wr * 64 + i * 16 + r;
                af[i] = *(const half8*)(Al + row * 64 + (((4 * ks + g) ^ (row & 7)) << 3));
                int rowb = wc * 64 + i * 16 + r;
                bf[i] = *(const half8*)(Bl + rowb * 64 + (((4 * ks + g) ^ (rowb & 7)) << 3));
            }
#pragma unroll
            for (int i = 0; i < 4; i++)
#pragma unroll
                for (int j = 0; j < 4; j++)
                    acc[i][j] = __builtin_amdgcn_mfma_f32_16x16x32_f16(af[i], bf[j], acc[i][j], 0, 0, 0);
        }
        __syncthreads();
    }

#pragma unroll
    for (int i = 0; i < 4; i++)
#pragma unroll
        for (int j = 0; j < 4; j++) {
            int gcol = n0 + wc * 64 + j * 16 + r;
            float bv = bias[gcol];
#pragma unroll
            for (int rr = 0; rr < 4; rr++) {
                int grow = m0 + wr * 64 + i * 16 + g * 4 + rr;
                out[(size_t)grow * 1024 + gcol] = acc[i][j][rr] + bv;
            }
        }
}

// ---------------- launch ----------------
extern "C" void kernel_launch(void* const* d_in, const int* in_sizes, int n_in,
                              void* d_out, int out_size, void* d_ws, size_t ws_size,
                              hipStream_t stream) {
    const float* x = (const float*)d_in[0];
    const float* Wqkv = (const float*)d_in[1];
    const float* Wproj = (const float*)d_in[2];
    const float* bproj = (const float*)d_in[3];
    const float* qscale = (const float*)d_in[4];
    const float* kscale = (const float*)d_in[5];
    float* out = (float*)d_out;

    char* ws = (char*)d_ws;
    half_t* xh  = (half_t*)(ws + 0);         //  8.0 MB (4096 x 1024 fp16)
    half_t* wqt = (half_t*)(ws + 8388608);   //  6.0 MB (3072 x 1024 fp16, transposed)
    half_t* wpt = (half_t*)(ws + 14680064);  //  2.0 MB (1024 x 1024 fp16, transposed)
    half_t* qh  = (half_t*)(ws + 16777216);  //  8.0 MB (b,h,n,f)
    half_t* kh  = (half_t*)(ws + 25165824);  //  8.0 MB (b,h,n,f)
    half_t* vth = (half_t*)(ws + 33554432);  //  8.0 MB (b,h,f,n)
    half_t* aoh = (half_t*)(ws + 41943040);  //  8.0 MB (b,n,c)

    prep_all<<<8192, 256, 0, stream>>>(x, Wqkv, Wproj, xh, wqt, wpt);
    gemm_qkv<<<dim3(32, 24), 256, 0, stream>>>(xh, wqt, qscale, kscale, qh, kh, vth);
    attn<<<dim3(32, 32), 256, 0, stream>>>(qh, kh, vth, aoh);
    gemm_proj<<<dim3(32, 8), 256, 0, stream>>>(aoh, wpt, bproj, out);
}

// Round 9
// 130.757 us; speedup vs baseline: 1.0350x; 1.0350x over previous
//
#include <hip/hip_runtime.h>

// Problem constants: B=2, N=2048, C=1024, H=16, hd=64
// x:(2,2048,1024) f32; Wqkv:(1024,3072); Wproj:(1024,1024); bproj:(1024); q_scale,k_scale:(64)
// out:(2,2048,1024) f32

typedef _Float16 half_t;
typedef __attribute__((ext_vector_type(2))) __fp16 fp16x2;
typedef __attribute__((ext_vector_type(4))) _Float16 half4v;
typedef __attribute__((ext_vector_type(8))) _Float16 half8;
typedef __attribute__((ext_vector_type(4))) float f32x4;

#define DI __device__ __forceinline__

DI void gl_lds16(const void* g, void* l) {
    __builtin_amdgcn_global_load_lds((const __attribute__((address_space(1))) void*)g,
                                     (__attribute__((address_space(3))) void*)l, 16, 0, 0);
}

DI float exp2_fast(float x) {
    float r;
    asm("v_exp_f32 %0, %1" : "=v"(r) : "v"(x));
    return r;
}

// ---------------- merged prep kernel ----------------
// blocks [0,4096): x f32->fp16 ; [4096,7168): Wqkv transpose->fp16 ; [7168,8192): Wproj
__global__ void prep_all(const float* __restrict__ x, const float* __restrict__ Wqkv,
                         const float* __restrict__ Wproj, half_t* __restrict__ xh,
                         half_t* __restrict__ wqt, half_t* __restrict__ wpt) {
    __shared__ float t[32][33];
    int bid = blockIdx.x;
    if (bid < 4096) {
        int i = (bid * 256 + threadIdx.x) * 4;
        float4 v = *(const float4*)(x + i);
        half4v o;
        o[0] = (half_t)v.x; o[1] = (half_t)v.y; o[2] = (half_t)v.z; o[3] = (half_t)v.w;
        *(half4v*)(xh + i) = o;
    } else if (bid < 4096 + 3072) {
        int i = bid - 4096;
        int c0 = (i % 96) * 32, r0 = (i / 96) * 32;
        int tx = threadIdx.x & 31, ty = threadIdx.x >> 5;
#pragma unroll
        for (int k = 0; k < 4; k++)
            t[ty + 8 * k][tx] = Wqkv[(size_t)(r0 + ty + 8 * k) * 3072 + c0 + tx];
        __syncthreads();
#pragma unroll
        for (int k = 0; k < 4; k++)
            wqt[(size_t)(c0 + ty + 8 * k) * 1024 + r0 + tx] = (half_t)t[tx][ty + 8 * k];
    } else {
        int i = bid - 4096 - 3072;
        int c0 = (i % 32) * 32, r0 = (i / 32) * 32;
        int tx = threadIdx.x & 31, ty = threadIdx.x >> 5;
#pragma unroll
        for (int k = 0; k < 4; k++)
            t[ty + 8 * k][tx] = Wproj[(size_t)(r0 + ty + 8 * k) * 1024 + c0 + tx];
        __syncthreads();
#pragma unroll
        for (int k = 0; k < 4; k++)
            wpt[(size_t)(c0 + ty + 8 * k) * 1024 + r0 + tx] = (half_t)t[tx][ty + 8 * k];
    }
}

// ---------------- QKV GEMM: fp16, BK=64, dbuf LDS, fused RMSNorm epilogue ----------------
__global__ __launch_bounds__(256) void gemm_qkv(
    const half_t* __restrict__ A, const half_t* __restrict__ Bt,
    const float* __restrict__ qs, const float* __restrict__ ks,
    half_t* __restrict__ qh, half_t* __restrict__ kh, half_t* __restrict__ vth) {
    const int K = 1024;
    __shared__ __align__(16) half_t Al[2][128 * 64];
    __shared__ __align__(16) half_t Bl[2][128 * 64];
    int tid = threadIdx.x;
    int w = tid >> 6, l = tid & 63;
    int wr = w >> 1, wc = w & 1;
    int g = l >> 4, r = l & 15;
    int m0 = blockIdx.x * 128, n0 = blockIdx.y * 128;
    f32x4 acc[4][4] = {};

#define STAGE_QKV(kt, buf)                                                        \
    {                                                                             \
        _Pragma("unroll")                                                         \
        for (int p = 0; p < 4; p++) {                                             \
            int ci = p * 256 + tid;                                               \
            int row = ci >> 3, c = ci & 7, lc = c ^ (row & 7);                    \
            gl_lds16(A + (size_t)(m0 + row) * K + (kt) * 64 + lc * 8,             \
                     &Al[buf][0] + ci * 8);                                       \
            gl_lds16(Bt + (size_t)(n0 + row) * K + (kt) * 64 + lc * 8,            \
                     &Bl[buf][0] + ci * 8);                                       \
        }                                                                         \
    }

    STAGE_QKV(0, 0);
    __syncthreads();
    int cur = 0;
    for (int kt = 0; kt < 16; kt++) {
        if (kt < 15) STAGE_QKV(kt + 1, cur ^ 1);
#pragma unroll
        for (int ks2 = 0; ks2 < 2; ks2++) {
            half8 af[4], bf[4];
#pragma unroll
            for (int i = 0; i < 4; i++) {
                int row = wr * 64 + i * 16 + r;
                af[i] = *(const half8*)(&Al[cur][0] + row * 64 + (((4 * ks2 + g) ^ (row & 7)) << 3));
                int rowb = wc * 64 + i * 16 + r;
                bf[i] = *(const half8*)(&Bl[cur][0] + rowb * 64 + (((4 * ks2 + g) ^ (rowb & 7)) << 3));
            }
#pragma unroll
            for (int i = 0; i < 4; i++)
#pragma unroll
                for (int j = 0; j < 4; j++)
                    acc[i][j] = __builtin_amdgcn_mfma_f32_16x16x32_f16(af[i], bf[j], acc[i][j], 0, 0, 0);
        }
        __syncthreads();
        cur ^= 1;
    }

    int tsec = n0 >> 10;  // 0=q, 1=k, 2=v (uniform per block)
    if (tsec == 2) {
#pragma unroll
        for (int i = 0; i < 4; i++)
#pragma unroll
            for (int j = 0; j < 4; j++) {
                int gcol = n0 + wc * 64 + j * 16 + r;
                int h = (gcol >> 6) & 15;
                int f = gcol & 63;
                int growb = m0 + wr * 64 + i * 16 + g * 4;
                int b = growb >> 11;
                int n = growb & 2047;
                half4v pv;
#pragma unroll
                for (int rr = 0; rr < 4; rr++) pv[rr] = (half_t)acc[i][j][rr];
                *(half4v*)(vth + ((size_t)(b * 16 + h) * 64 + f) * 2048 + n) = pv;
            }
    } else {
        const float* sc = (tsec == 0) ? qs : ks;
        half_t* dst = (tsec == 0) ? qh : kh;
        float extra = (tsec == 0) ? (0.125f * 1.44269504f) : 1.0f;  // fold hd^-0.5*log2e into q
        float scv[4];
#pragma unroll
        for (int j = 0; j < 4; j++) scv[j] = sc[j * 16 + r];
#pragma unroll
        for (int i = 0; i < 4; i++)
#pragma unroll
            for (int rr = 0; rr < 4; rr++) {
                float ss = 0.f;
#pragma unroll
                for (int j = 0; j < 4; j++) ss += acc[i][j][rr] * acc[i][j][rr];
#pragma unroll
                for (int d = 1; d < 16; d <<= 1) ss += __shfl_xor(ss, d, 64);
                float inv = extra / (sqrtf(ss) * 0.125f + 1e-8f);  // rms = ||row||/8
                int grow = m0 + wr * 64 + i * 16 + g * 4 + rr;
                int b = grow >> 11;
                int n = grow & 2047;
#pragma unroll
                for (int j = 0; j < 4; j++) {
                    int gcol = n0 + wc * 64 + j * 16 + r;
                    int h = (gcol >> 6) & 15;
                    int f = gcol & 63;
                    dst[((size_t)(b * 16 + h) * 2048 + n) * 64 + f] =
                        (half_t)(acc[i][j][rr] * inv * scv[j]);
                }
            }
    }
}

// ---------------- flash attention, one-tile score pipeline -------------------------
// grid (16 q-tiles, 32 bh), 512 thr = 8 waves, 16 q-rows/wave (1 q/lane).
// Pipeline: iteration t computes S(t) = mfma(K(t),Q) but consumes S(t-1)
// (softmax + PV). softmax(S_prev) has no dependency on the just-issued QK(t)
// MFMAs -> the ~50-80cy S-consume stall disappears (T15 mechanism, within-wave).
// K,V triple-buffered LDS (V(t-1) must survive while t+1 stages); 2 S-register
// sets (even/odd tile); loop unrolled x6 = lcm(2,3) so all indices are static.
// One barrier per tile. Numerics identical to R7 (same per-tile op order).
// Defer-max THR=11 (PROVEN; no-max variant failed 4.7e-2 — keep max tracking).
__global__ __launch_bounds__(512, 4) void attn(
    const half_t* __restrict__ qh, const half_t* __restrict__ kh,
    const half_t* __restrict__ vth, half_t* __restrict__ aoh) {
    int bh = blockIdx.y;
    int q0 = blockIdx.x * 128;
    const half_t* Qp = qh + (size_t)bh * 2048 * 64;
    const half_t* Kp = kh + (size_t)bh * 2048 * 64;
    const half_t* Vp = vth + (size_t)bh * 64 * 2048;  // (feat, n)
    __shared__ __align__(16) half_t Kl[3][64 * 64];
    __shared__ __align__(16) half_t Vl[3][64 * 64];   // [feat][kv]
    __shared__ __align__(16) half_t Pl[8][16 * 64];   // per-wave: 16 q x 64 kv (chunk-swizzled)
    int tid = threadIdx.x, w = tid >> 6, l = tid & 63, g = l >> 4, r = l & 15;

    // staging: 512 chunks of 16B per 64x64 fp16 buffer, 1 chunk/thread
    int srow = tid >> 3, sc = tid & 7, slc = sc ^ (srow & 7);
    const half_t* kst = Kp + (size_t)srow * 64 + slc * 8;
    const half_t* vst = Vp + (size_t)srow * 2048 + slc * 8;

    // hoisted LDS element-offsets (loop-invariant)
    int koff[8], voff[8], poffw[4], poffr[2];
#pragma unroll
    for (int ks = 0; ks < 2; ks++)
#pragma unroll
        for (int tt = 0; tt < 4; tt++) {
            int row = tt * 16 + r;
            koff[ks * 4 + tt] = row * 64 + (((4 * ks + g) ^ (row & 7)) << 3);
        }
#pragma unroll
    for (int ks2 = 0; ks2 < 2; ks2++)
#pragma unroll
        for (int cf = 0; cf < 4; cf++) {
            int row = cf * 16 + r;
            voff[ks2 * 4 + cf] = row * 64 + (((4 * ks2 + g) ^ (row & 7)) << 3);
        }
#pragma unroll
    for (int tt = 0; tt < 4; tt++)
        poffw[tt] = r * 64 + (((2 * tt + (g >> 1)) ^ (r & 7)) << 3) + (g & 1) * 4;
#pragma unroll
    for (int ks2 = 0; ks2 < 2; ks2++)
        poffr[ks2] = r * 64 + (((4 * ks2 + g) ^ (r & 7)) << 3);
    half_t* Pw = &Pl[w][0];

    // Q fragment: Q[q=r][hd = 32ks + 8g + e]  (B-operand of swapped QK^T)
    half8 qf[2];
#pragma unroll
    for (int ks = 0; ks < 2; ks++)
        qf[ks] = *(const half8*)(Qp + (size_t)(q0 + w * 16 + r) * 64 + ks * 32 + g * 8);

    f32x4 o[4] = {};          // O^T[d = 16cf + 4g + reg][q = r]
    f32x4 sE[4], sO[4];       // score sets for even/odd tiles
    float m = -1e30f, lsum = 0.f;  // lsum: per-lane partial, reduced in epilogue

#define STAGE_T(T, IDX)                                                            \
    {                                                                              \
        gl_lds16(kst + (T) * 4096, &Kl[IDX][0] + tid * 8);                         \
        gl_lds16(vst + (T) * 64, &Vl[IDX][0] + tid * 8);                           \
    }

// compute S-set from K buffer KB (8 MFMA, result consumed next iteration)
#define QK_STEP(KB, S)                                                             \
    {                                                                              \
        const half_t* Kc = &Kl[KB][0];                                             \
        _Pragma("unroll")                                                          \
        for (int tt = 0; tt < 4; tt++) S[tt] = (f32x4){0.f, 0.f, 0.f, 0.f};        \
        _Pragma("unroll")                                                          \
        for (int ks = 0; ks < 2; ks++)                                             \
            _Pragma("unroll")                                                      \
            for (int tt = 0; tt < 4; tt++) {                                       \
                half8 kf = *(const half8*)(Kc + koff[ks * 4 + tt]);                \
                S[tt] = __builtin_amdgcn_mfma_f32_16x16x32_f16(kf, qf[ks], S[tt], 0, 0, 0); \
            }                                                                      \
    }

// softmax + pack + PV for the previous tile (scores S, V buffer VB)
#define SM_PV(S, VB)                                                               \
    {                                                                              \
        float mx = -1e30f;                                                         \
        _Pragma("unroll")                                                          \
        for (int tt = 0; tt < 4; tt++)                                             \
            mx = fmaxf(mx, fmaxf(fmaxf(S[tt][0], S[tt][1]), fmaxf(S[tt][2], S[tt][3]))); \
        mx = fmaxf(mx, __shfl_xor(mx, 16, 64));                                    \
        mx = fmaxf(mx, __shfl_xor(mx, 32, 64));                                    \
        if (!__all(mx <= m + 11.0f)) {                                             \
            float mn = fmaxf(m, mx);                                               \
            float fac = exp2_fast(m - mn);                                         \
            lsum *= fac;                                                           \
            _Pragma("unroll")                                                      \
            for (int cf = 0; cf < 4; cf++) {                                       \
                o[cf][0] *= fac; o[cf][1] *= fac; o[cf][2] *= fac; o[cf][3] *= fac; \
            }                                                                      \
            m = mn;                                                                \
        }                                                                          \
        _Pragma("unroll")                                                          \
        for (int tt = 0; tt < 4; tt++)                                             \
            _Pragma("unroll")                                                      \
            for (int e = 0; e < 4; e++) {                                          \
                float p = exp2_fast(S[tt][e] - m);                                 \
                S[tt][e] = p;                                                      \
                lsum += p;                                                         \
            }                                                                      \
        _Pragma("unroll")                                                          \
        for (int tt = 0; tt < 4; tt++) {                                           \
            fp16x2 a = __builtin_amdgcn_cvt_pkrtz(S[tt][0], S[tt][1]);             \
            fp16x2 b = __builtin_amdgcn_cvt_pkrtz(S[tt][2], S[tt][3]);             \
            half4v v4;                                                             \
            v4[0] = (half_t)a[0]; v4[1] = (half_t)a[1];                            \
            v4[2] = (half_t)b[0]; v4[3] = (half_t)b[1];                            \
            *(half4v*)(Pw + poffw[tt]) = v4;                                       \
        }                                                                          \
        const half_t* Vc = &Vl[VB][0];                                             \
        _Pragma("unroll")                                                          \
        for (int ks2 = 0; ks2 < 2; ks2++) {                                        \
            half8 pf = *(const half8*)(Pw + poffr[ks2]);                           \
            _Pragma("unroll")                                                      \
            for (int cf = 0; cf < 4; cf++) {                                       \
                half8 vf = *(const half8*)(Vc + voff[ks2 * 4 + cf]);               \
                o[cf] = __builtin_amdgcn_mfma_f32_16x16x32_f16(vf, pf, o[cf], 0, 0, 0); \
            }                                                                      \
        }                                                                          \
    }

    // prologue: tile 0 staged + scored; tile 1 staged
    STAGE_T(0, 0);
    __syncthreads();
    QK_STEP(0, sE);
    STAGE_T(1, 1);
    __syncthreads();

    // steady state: tiles 1..30, unroll x6 (S parity 2 x buffer mod 3)
    for (int k = 0; k < 5; k++) {
        QK_STEP(1, sO); STAGE_T(6 * k + 2, 2); SM_PV(sE, 0); __syncthreads();
        QK_STEP(2, sE); STAGE_T(6 * k + 3, 0); SM_PV(sO, 1); __syncthreads();
        QK_STEP(0, sO); STAGE_T(6 * k + 4, 1); SM_PV(sE, 2); __syncthreads();
        QK_STEP(1, sE); STAGE_T(6 * k + 5, 2); SM_PV(sO, 0); __syncthreads();
        QK_STEP(2, sO); STAGE_T(6 * k + 6, 0); SM_PV(sE, 1); __syncthreads();
        QK_STEP(0, sE); STAGE_T(6 * k + 7, 1); SM_PV(sO, 2); __syncthreads();
    }

    // epilogue: score tile 31 (buf 1), consume tiles 30 (buf 0) and 31 (buf 1)
    QK_STEP(1, sO);
    SM_PV(sE, 0);
    SM_PV(sO, 1);

    // cross-lane (g-group) sum: lanes r, r+16, r+32, r+48 hold disjoint kv-slots
    lsum += __shfl_xor(lsum, 16, 64);
    lsum += __shfl_xor(lsum, 32, 64);

    int b = bh >> 4, h = bh & 15;
    int n = q0 + w * 16 + r;
    float inv = 1.0f / lsum;
#pragma unroll
    for (int cf = 0; cf < 4; cf++) {
        half4v ov;
#pragma unroll
        for (int reg = 0; reg < 4; reg++) ov[reg] = (half_t)(o[cf][reg] * inv);
        *(half4v*)(aoh + ((size_t)b * 2048 + n) * 1024 + h * 64 + cf * 16 + g * 4) = ov;
    }
}

// ---------------- proj GEMM: fp16, BK=64, + bias, f32 out ----------------
__global__ __launch_bounds__(256) void gemm_proj(
    const half_t* __restrict__ A, const half_t* __restrict__ Bt,
    const float* __restrict__ bias, float* __restrict__ out) {
    const int K = 1024;
    __shared__ __align__(16) half_t Al[128 * 64];
    __shared__ __align__(16) half_t Bl[128 * 64];
    int tid = threadIdx.x, w = tid >> 6, l = tid & 63;
    int wr = w >> 1, wc = w & 1, g = l >> 4, r = l & 15;
    int m0 = blockIdx.x * 128, n0 = blockIdx.y * 128;
    f32x4 acc[4][4] = {};

    for (int k0 = 0; k0 < K; k0 += 64) {
#pragma unroll
        for (int p = 0; p < 4; p++) {
            int ci = (p * 4 + w) * 64 + l;
            int row = ci >> 3, c = ci & 7;
            int lc = c ^ (row & 7);
            gl_lds16(A + (size_t)(m0 + row) * K + k0 + lc * 8, Al + (p * 4 + w) * 512);
            gl_lds16(Bt + (size_t)(n0 + row) * K + k0 + lc * 8, Bl + (p * 4 + w) * 512);
        }
        __syncthreads();
#pragma unroll
        for (int ks = 0; ks < 2; ks++) {
            half8 af[4], bf[4];
#pragma unroll
            for (int i = 0; i < 4; i++) {
                int row = wr * 64 + i * 16 + r;
                af[i] = *(const half8*)(Al + row * 64 + (((4 * ks + g) ^ (row & 7)) << 3));
                int rowb = wc * 64 + i * 16 + r;
                bf[i] = *(const half8*)(Bl + rowb * 64 + (((4 * ks + g) ^ (rowb & 7)) << 3));
            }
#pragma unroll
            for (int i = 0; i < 4; i++)
#pragma unroll
                for (int j = 0; j < 4; j++)
                    acc[i][j] = __builtin_amdgcn_mfma_f32_16x16x32_f16(af[i], bf[j], acc[i][j], 0, 0, 0);
        }
        __syncthreads();
    }

#pragma unroll
    for (int i = 0; i < 4; i++)
#pragma unroll
        for (int j = 0; j < 4; j++) {
            int gcol = n0 + wc * 64 + j * 16 + r;
            float bv = bias[gcol];
#pragma unroll
            for (int rr = 0; rr < 4; rr++) {
                int grow = m0 + wr * 64 + i * 16 + g * 4 + rr;
                out[(size_t)grow * 1024 + gcol] = acc[i][j][rr] + bv;
            }
        }
}

// ---------------- launch ----------------
extern "C" void kernel_launch(void* const* d_in, const int* in_sizes, int n_in,
                              void* d_out, int out_size, void* d_ws, size_t ws_size,
                              hipStream_t stream) {
    const float* x = (const float*)d_in[0];
    const float* Wqkv = (const float*)d_in[1];
    const float* Wproj = (const float*)d_in[2];
    const float* bproj = (const float*)d_in[3];
    const float* qscale = (const float*)d_in[4];
    const float* kscale = (const float*)d_in[5];
    float* out = (float*)d_out;

    char* ws = (char*)d_ws;
    half_t* xh  = (half_t*)(ws + 0);         //  8.0 MB (4096 x 1024 fp16)
    half_t* wqt = (half_t*)(ws + 8388608);   //  6.0 MB (3072 x 1024 fp16, transposed)
    half_t* wpt = (half_t*)(ws + 14680064);  //  2.0 MB (1024 x 1024 fp16, transposed)
    half_t* qh  = (half_t*)(ws + 16777216);  //  8.0 MB (b,h,n,f)
    half_t* kh  = (half_t*)(ws + 25165824);  //  8.0 MB (b,h,n,f)
    half_t* vth = (half_t*)(ws + 33554432);  //  8.0 MB (b,h,f,n)
    half_t* aoh = (half_t*)(ws + 41943040);  //  8.0 MB (b,n,c)

    prep_all<<<8192, 256, 0, stream>>>(x, Wqkv, Wproj, xh, wqt, wpt);
    gemm_qkv<<<dim3(32, 24), 256, 0, stream>>>(xh, wqt, qscale, kscale, qh, kh, vth);
    attn<<<dim3(16, 32), 512, 0, stream>>>(qh, kh, vth, aoh);
    gemm_proj<<<dim3(32, 8), 256, 0, stream>>>(aoh, wpt, bproj, out);
}